// Round 1
// baseline (183.048 us; speedup 1.0000x reference)
//
#include <hip/hip_runtime.h>
#include <math.h>

// Problem constants (match reference)
#define BB 64
#define DD 1024
#define GG 64

__device__ __forceinline__ float softplus_f(float z) {
    // numerically stable: max(z,0) + log1p(exp(-|z|))
    return fmaxf(z, 0.0f) + log1pf(__expf(-fabsf(z)));
}

// One 64-lane wave computes one output element (b,u):
//   dot over p of (w_mu[g,u,p] + softplus(w_sigma[g,u,p])*eps_w[b,u,p]) * x[b,p]
__global__ __launch_bounds__(256) void mld_kernel(
    const float* __restrict__ x, const int* __restrict__ gid,
    const float* __restrict__ w_mu, const float* __restrict__ w_sigma,
    const float* __restrict__ b_mu, const float* __restrict__ b_sigma,
    const float* __restrict__ eps_w, const float* __restrict__ eps_b,
    float* __restrict__ out)
{
    const int wave = (int)((blockIdx.x * blockDim.x + threadIdx.x) >> 6);
    const int lane = (int)(threadIdx.x & 63);
    const int b = wave >> 10;       // DD = 1024 outputs per sample
    const int u = wave & 1023;
    const int g = gid[b];

    const float4* __restrict__ xr  = (const float4*)(x + (size_t)b * DD);
    const float4* __restrict__ wmr = (const float4*)(w_mu    + ((size_t)g * DD + u) * DD);
    const float4* __restrict__ wsr = (const float4*)(w_sigma + ((size_t)g * DD + u) * DD);
    const float4* __restrict__ ewr = (const float4*)(eps_w   + ((size_t)b * DD + u) * DD);

    float acc = 0.0f;
    #pragma unroll
    for (int k = 0; k < 4; ++k) {
        const int i = lane + k * 64;       // 256 float4 per 1024-float row
        const float4 xm = xr[i];
        const float4 wm = wmr[i];
        const float4 ws = wsr[i];
        const float4 ew = ewr[i];
        acc += (wm.x + softplus_f(ws.x) * ew.x) * xm.x;
        acc += (wm.y + softplus_f(ws.y) * ew.y) * xm.y;
        acc += (wm.z + softplus_f(ws.z) * ew.z) * xm.z;
        acc += (wm.w + softplus_f(ws.w) * ew.w) * xm.w;
    }

    // wave-wide sum (64 lanes)
    #pragma unroll
    for (int off = 32; off > 0; off >>= 1)
        acc += __shfl_down(acc, off, 64);

    if (lane == 0) {
        const size_t gu = (size_t)g * DD + u;
        const size_t bu = (size_t)b * DD + u;
        const float bs = b_mu[gu] + softplus_f(b_sigma[gu]) * eps_b[bu];
        const float o = acc + bs;
        out[bu] = fmaxf(o, 0.0f);
    }
}

extern "C" void kernel_launch(void* const* d_in, const int* in_sizes, int n_in,
                              void* d_out, int out_size, void* d_ws, size_t ws_size,
                              hipStream_t stream) {
    const float* x       = (const float*)d_in[0];
    const int*   gid     = (const int*)d_in[1];
    const float* w_mu    = (const float*)d_in[2];
    const float* w_sigma = (const float*)d_in[3];
    const float* b_mu    = (const float*)d_in[4];
    const float* b_sigma = (const float*)d_in[5];
    const float* eps_w   = (const float*)d_in[6];
    const float* eps_b   = (const float*)d_in[7];
    float* out = (float*)d_out;

    // BB*DD output elements, one wave each; 4 waves (256 threads) per block.
    const int total_waves = BB * DD;           // 65536
    const int blocks = total_waves / 4;        // 16384
    mld_kernel<<<blocks, 256, 0, stream>>>(x, gid, w_mu, w_sigma, b_mu, b_sigma,
                                           eps_w, eps_b, out);
}

// Round 4
// 116.041 us; speedup vs baseline: 1.5774x; 1.5774x over previous
//
#include <hip/hip_runtime.h>
#include <math.h>

// Problem constants (match reference)
#define BB 64
#define DD 1024
#define GG 64

__device__ __forceinline__ float softplus_fast(float z) {
    // softplus(z) = max(z,0) + ln2 * log2(1 + exp2(-|z|*log2e))
    // __builtin_amdgcn_exp2f -> v_exp_f32; __builtin_amdgcn_logf -> v_log_f32 (log2).
    const float LOG2E = 1.44269504088896340736f;
    const float LN2   = 0.69314718055994530942f;
    float t = __builtin_amdgcn_exp2f(-LOG2E * fabsf(z));   // exp(-|z|)
    float l = __builtin_amdgcn_logf(1.0f + t);             // log2(1 + exp(-|z|))
    return fmaxf(z, 0.0f) + LN2 * l;
}

// One 64-lane wave computes one output element (b,u):
//   dot over p of (w_mu[g,u,p] + softplus(w_sigma[g,u,p])*eps_w[b,u,p]) * x[b,p]
__global__ __launch_bounds__(256) void mld_kernel(
    const float* __restrict__ x, const int* __restrict__ gid,
    const float* __restrict__ w_mu, const float* __restrict__ w_sigma,
    const float* __restrict__ b_mu, const float* __restrict__ b_sigma,
    const float* __restrict__ eps_w, const float* __restrict__ eps_b,
    float* __restrict__ out)
{
    const int wave = (int)((blockIdx.x * blockDim.x + threadIdx.x) >> 6);
    const int lane = (int)(threadIdx.x & 63);
    const int b = wave >> 10;       // DD = 1024 outputs per sample
    const int u = wave & 1023;
    const int g = gid[b];

    const float4* __restrict__ xr  = (const float4*)(x + (size_t)b * DD);
    const float4* __restrict__ wmr = (const float4*)(w_mu    + ((size_t)g * DD + u) * DD);
    const float4* __restrict__ wsr = (const float4*)(w_sigma + ((size_t)g * DD + u) * DD);
    const float4* __restrict__ ewr = (const float4*)(eps_w   + ((size_t)b * DD + u) * DD);

    float acc = 0.0f;
    #pragma unroll
    for (int k = 0; k < 4; ++k) {
        const int i = lane + k * 64;       // 256 float4 per 1024-float row
        const float4 xm = xr[i];
        const float4 wm = wmr[i];
        const float4 ws = wsr[i];
        const float4 ew = ewr[i];
        acc += (wm.x + softplus_fast(ws.x) * ew.x) * xm.x;
        acc += (wm.y + softplus_fast(ws.y) * ew.y) * xm.y;
        acc += (wm.z + softplus_fast(ws.z) * ew.z) * xm.z;
        acc += (wm.w + softplus_fast(ws.w) * ew.w) * xm.w;
    }

    // wave-wide sum (64 lanes)
    #pragma unroll
    for (int off = 32; off > 0; off >>= 1)
        acc += __shfl_down(acc, off, 64);

    if (lane == 0) {
        const size_t gu = (size_t)g * DD + u;
        const size_t bu = (size_t)b * DD + u;
        const float bs = b_mu[gu] + softplus_fast(b_sigma[gu]) * eps_b[bu];
        const float o = acc + bs;
        out[bu] = fmaxf(o, 0.0f);
    }
}

extern "C" void kernel_launch(void* const* d_in, const int* in_sizes, int n_in,
                              void* d_out, int out_size, void* d_ws, size_t ws_size,
                              hipStream_t stream) {
    const float* x       = (const float*)d_in[0];
    const int*   gid     = (const int*)d_in[1];
    const float* w_mu    = (const float*)d_in[2];
    const float* w_sigma = (const float*)d_in[3];
    const float* b_mu    = (const float*)d_in[4];
    const float* b_sigma = (const float*)d_in[5];
    const float* eps_w   = (const float*)d_in[6];
    const float* eps_b   = (const float*)d_in[7];
    float* out = (float*)d_out;

    // BB*DD output elements, one wave each; 4 waves (256 threads) per block.
    const int total_waves = BB * DD;           // 65536
    const int blocks = total_waves / 4;        // 16384
    mld_kernel<<<blocks, 256, 0, stream>>>(x, gid, w_mu, w_sigma, b_mu, b_sigma,
                                           eps_w, eps_b, out);
}